// Round 6
// baseline (188.836 us; speedup 1.0000x reference)
//
#include <hip/hip_runtime.h>
#include <stdint.h>
#include <stddef.h>

typedef __bf16 bf16;
typedef __bf16 bf16x4 __attribute__((ext_vector_type(4)));
typedef __bf16 bf16x8 __attribute__((ext_vector_type(8)));
typedef float  f32x4  __attribute__((ext_vector_type(4)));
typedef float  f32x16 __attribute__((ext_vector_type(16)));
typedef float  f32x4v __attribute__((ext_vector_type(4)));
typedef unsigned int u32x4 __attribute__((ext_vector_type(4)));

// async global->LDS, 16B per lane, wave-uniform LDS base + lane*16
__device__ __forceinline__ void gload_lds16(const void* g, void* lds) {
  __builtin_amdgcn_global_load_lds(
      (__attribute__((address_space(1))) void*)(uintptr_t)g,
      (__attribute__((address_space(3))) void*)lds,
      16, 0, 0);
}

__device__ __forceinline__ unsigned int pk2(float a, float b) {
  unsigned short lo = __builtin_bit_cast(unsigned short, (bf16)a);
  unsigned short hi = __builtin_bit_cast(unsigned short, (bf16)b);
  return (unsigned int)lo | ((unsigned int)hi << 16);
}

// ---------------- conversion kernels ----------------

__global__ void cvt_f32_to_bf16(const float* __restrict__ in, bf16* __restrict__ out, int n) {
  int i = (blockIdx.x * blockDim.x + threadIdx.x) * 4;
  if (i >= n) return;
  f32x4v v = *reinterpret_cast<const f32x4v*>(in + i);
  bf16x4 o;
  o[0] = (bf16)v[0]; o[1] = (bf16)v[1]; o[2] = (bf16)v[2]; o[3] = (bf16)v[3];
  *reinterpret_cast<bf16x4*>(out + i) = o;
}

// in [R][C] f32  ->  out [C][R] bf16   (R,C multiples of 32)
__global__ void transpose_cvt(const float* __restrict__ in, bf16* __restrict__ out, int R, int C) {
  __shared__ bf16 tile[32][33];
  int c0 = blockIdx.x * 32, r0 = blockIdx.y * 32;
  int tx = threadIdx.x, ty = threadIdx.y;
  #pragma unroll
  for (int i = ty; i < 32; i += 8)
    tile[i][tx] = (bf16)in[(size_t)(r0 + i) * C + (c0 + tx)];
  __syncthreads();
  #pragma unroll
  for (int i = ty; i < 32; i += 8)
    out[(size_t)(c0 + i) * R + (r0 + tx)] = tile[tx][i];
}

// ---------------- GEMM: C[M][N] = A[M][K] * Bt[N][K]^T (+bias) ----------------
// 128x128 tile, BK=64, 4 waves in 2x2, each wave 64x64 (4x4 16x16 fragments).

template <typename OT, bool BIAS>
__global__ __launch_bounds__(256) void gemm_abt(
    const bf16* __restrict__ A,   // [M][K]
    const bf16* __restrict__ Bt,  // [N][K]
    const float* __restrict__ bias,
    OT* __restrict__ C, int M, int N, int K)
{
  __shared__ bf16 As[128 * 64];
  __shared__ bf16 Bs[128 * 64];

  const int tid = threadIdx.x;
  const int w = tid >> 6, l = tid & 63;
  const int l15 = l & 15, l4 = l >> 4, l7 = l & 7;
  const int wr = w >> 1, wc = w & 1;
  const int m0 = blockIdx.y * 128, n0 = blockIdx.x * 128;

  f32x4 acc[4][4];
  #pragma unroll
  for (int i = 0; i < 4; i++)
    #pragma unroll
    for (int j = 0; j < 4; j++) acc[i][j] = (f32x4){0.f, 0.f, 0.f, 0.f};

  const int srow  = w * 8 + (l >> 3);            // + p*32
  const int sslot = (l & 7) ^ ((l >> 3) & 7);    // pre-swizzled 16B slot (row&7 = l>>3)
  const int KT = K >> 6;

  for (int kt = 0; kt < KT; ++kt) {
    __syncthreads();                              // prior compute done reading LDS
    const int kcol = kt * 64 + sslot * 8;
    #pragma unroll
    for (int p = 0; p < 4; ++p) {
      gload_lds16(A  + (size_t)(m0 + p * 32 + srow) * K + kcol,
                  (char*)As + p * 4096 + w * 1024);
      gload_lds16(Bt + (size_t)(n0 + p * 32 + srow) * K + kcol,
                  (char*)Bs + p * 4096 + w * 1024);
    }
    __syncthreads();                              // staging complete (vmcnt drained)

    #pragma unroll
    for (int kk = 0; kk < 2; ++kk) {
      const int coff = (kk * 32 + l4 * 8) ^ (l7 << 3);
      bf16x8 af[4], bq[4];
      #pragma unroll
      for (int m = 0; m < 4; ++m) {
        int r = wr * 64 + m * 16 + l15;           // r&7 == l7
        af[m] = *reinterpret_cast<const bf16x8*>(&As[r * 64 + coff]);
      }
      #pragma unroll
      for (int n = 0; n < 4; ++n) {
        int r = wc * 64 + n * 16 + l15;
        bq[n] = *reinterpret_cast<const bf16x8*>(&Bs[r * 64 + coff]);
      }
      #pragma unroll
      for (int m = 0; m < 4; ++m)
        #pragma unroll
        for (int n = 0; n < 4; ++n)
          acc[m][n] = __builtin_amdgcn_mfma_f32_16x16x32_bf16(af[m], bq[n], acc[m][n], 0, 0, 0);
    }
  }

  // epilogue: D[row][col], col = lane&15, row = (lane>>4)*4 + j
  #pragma unroll
  for (int m = 0; m < 4; ++m) {
    #pragma unroll
    for (int n = 0; n < 4; ++n) {
      int col = n0 + wc * 64 + n * 16 + l15;
      float bv = BIAS ? bias[col] : 0.f;
      #pragma unroll
      for (int j = 0; j < 4; ++j) {
        int row = m0 + wr * 64 + m * 16 + l4 * 4 + j;
        float v = acc[m][n][j] + bv;
        C[(size_t)row * N + col] = (OT)v;
      }
    }
  }
}

// ---------------- fused flash attention (32x32x16, P fully in registers) ---
// qkv [8192][3072] bf16. One block = 4 waves, 128 q-rows (32/wave),
// 16 K/V tiles of 64 keys. Fixed-shift softmax (|s|<~2, exact by shift
// invariance). Swapped QK^T: lane holds S^T[key=(reg&3)+8*(reg>>2)+4*hi][q=l31].
//
// PV uses a PERMUTATION-CONSISTENT fragment pair (no cross-lane, no P LDS):
// MFMA pairs A-lane and B-lane with the same hi for each k-slot, so applying
// per-hi key permutation pi_hi(e) = 4*hi + (e&3) + 8*(e>>2) to BOTH operands
// leaves the contraction invariant. A-frag = pk of the lane's own S regs in
// natural order; B-frag = V read in pi order (two ds_read_b64 per row at
// chunks (ktile*4+g*2)^(d&7) and (ktile*4+g*2+1)^(d&7), 8B offset hi*4).
//
// Row-sums via ones-B MFMA into accS (permutation sums all 16 slots), so
// the epilogue needs no shuffles: rinv = 1/accS[reg].

__global__ __launch_bounds__(256) void attn_fused(
    const bf16* __restrict__ qkv,
    bf16* __restrict__ aout)      // [8192][1024], col = h*64+d
{
  __shared__ bf16 Ks[64 * 64];      // [key][d], source-swizzled 16B slots
  __shared__ bf16 Vt[64 * 64];      // [d][key], swizzled

  const int tid = threadIdx.x;
  const int w = tid >> 6, l = tid & 63;
  const int l31 = l & 31, hi = l >> 5;

  // XCD-grouped swizzle: all 8 q-tiles of one (b,h) on one XCD for K/V L2 reuse
  const int bid = blockIdx.x;
  const int c  = bid & 7, rr = bid >> 3;
  const int g  = c * 16 + (rr & 15);     // 0..127 = b*16+h
  const int qt = rr >> 4;                // 0..7
  const int h  = g & 15;
  const int b  = g >> 4;

  const bf16* base = qkv + (size_t)b * 1024 * 3072;
  const int qrow0 = qt * 128 + w * 32;

  // Q B-fragments: qf[st] = Q[qrow0 + l31][st*16 + hi*8 + e], pre-scaled
  const float qscale = 0.03125f * 1.44269504f;   // D^-0.5 * log2(e)
  bf16x8 qf[4];
  #pragma unroll
  for (int st = 0; st < 4; st++) {
    const bf16* p = base + (size_t)(qrow0 + l31) * 3072 + h * 64 + st * 16 + hi * 8;
    bf16x8 v = *reinterpret_cast<const bf16x8*>(p);
    #pragma unroll
    for (int e = 0; e < 8; e++) v[e] = (bf16)((float)v[e] * qscale);
    qf[st] = v;
  }

  bf16x8 onesf;
  #pragma unroll
  for (int e = 0; e < 8; e++) onesf[e] = (bf16)1.0f;

  f32x16 acc0 = {}, acc1 = {}, accS = {};   // dtile 0 / 1 / row-sum

  const int skey  = w * 8 + (l >> 3);            // + p*32
  const int sslot = (l & 7) ^ ((l >> 3) & 7);
  // V quad staging: thread covers keys vk0..vk0+3, d vd0..vd0+3
  const int vd0   = (tid & 15) * 4;
  const int vk0   = (tid >> 4) * 4;
  const int vslot = tid >> 5;                    // 16B slot of key quad
  const int vhalf = (tid >> 4) & 1;              // 8B half

  for (int kt = 0; kt < 16; ++kt) {
    __syncthreads();
    // K tile -> LDS (async, pre-swizzled source column)
    #pragma unroll
    for (int p = 0; p < 2; ++p)
      gload_lds16(base + (size_t)(kt * 64 + p * 32 + skey) * 3072 + 1024 + h * 64 + sslot * 8,
                  (char*)Ks + p * 4096 + w * 1024);
    // V tile: 4x4 quad -> register transpose -> packed b64 LDS writes
    {
      bf16x4 vv[4];
      #pragma unroll
      for (int i = 0; i < 4; ++i)
        vv[i] = *reinterpret_cast<const bf16x4*>(
            base + (size_t)(kt * 64 + vk0 + i) * 3072 + 2048 + h * 64 + vd0);
      #pragma unroll
      for (int j = 0; j < 4; ++j) {
        int d = vd0 + j;
        bf16x4 o; o[0] = vv[0][j]; o[1] = vv[1][j]; o[2] = vv[2][j]; o[3] = vv[3][j];
        *reinterpret_cast<bf16x4*>(&Vt[d * 64 + ((vslot ^ (d & 7)) * 8 + vhalf * 4)]) = o;
      }
    }
    __syncthreads();

    #pragma unroll
    for (int ktile = 0; ktile < 2; ++ktile) {
      // QK^T for 32 keys
      f32x16 s = {};
      const int key = ktile * 32 + l31;
      #pragma unroll
      for (int st = 0; st < 4; ++st) {
        const int slot = (2 * st + hi) ^ (key & 7);
        bf16x8 kf = *reinterpret_cast<const bf16x8*>(&Ks[key * 64 + slot * 8]);
        s = __builtin_amdgcn_mfma_f32_32x32x16_bf16(kf, qf[st], s, 0, 0, 0);
      }
      // P = exp2(s) in place
      #pragma unroll
      for (int r = 0; r < 16; ++r) s[r] = exp2f(s[r]);
      // A-frags in natural reg order (keys pi_hi(e) per 16-key group)
      u32x4 dw0 = {pk2(s[0], s[1]),  pk2(s[2], s[3]),
                   pk2(s[4], s[5]),  pk2(s[6], s[7])};
      u32x4 dw1 = {pk2(s[8], s[9]),  pk2(s[10], s[11]),
                   pk2(s[12], s[13]), pk2(s[14], s[15])};
      bf16x8 pf0 = __builtin_bit_cast(bf16x8, dw0);
      bf16x8 pf1 = __builtin_bit_cast(bf16x8, dw1);

      // row sums (ones-B sums all 16 slots; permutation-invariant)
      accS = __builtin_amdgcn_mfma_f32_32x32x16_bf16(pf0, onesf, accS, 0, 0, 0);
      accS = __builtin_amdgcn_mfma_f32_32x32x16_bf16(pf1, onesf, accS, 0, 0, 0);

      // O += P V with pi-ordered V B-frags (two b64 reads per row)
      #pragma unroll
      for (int gg = 0; gg < 2; ++gg) {
        bf16x8 pf = gg ? pf1 : pf0;
        const int cb = ktile * 4 + gg * 2;
        const int d7 = l31 & 7;          // (32+l31)&7 identical
        bf16x4 a0 = *reinterpret_cast<const bf16x4*>(
            &Vt[l31 * 64 + ((cb ^ d7) * 8 + hi * 4)]);
        bf16x4 b0 = *reinterpret_cast<const bf16x4*>(
            &Vt[l31 * 64 + (((cb + 1) ^ d7) * 8 + hi * 4)]);
        bf16x8 vf0;
        #pragma unroll
        for (int e = 0; e < 4; ++e) { vf0[e] = a0[e]; vf0[4 + e] = b0[e]; }
        acc0 = __builtin_amdgcn_mfma_f32_32x32x16_bf16(pf, vf0, acc0, 0, 0, 0);

        bf16x4 a1 = *reinterpret_cast<const bf16x4*>(
            &Vt[(32 + l31) * 64 + ((cb ^ d7) * 8 + hi * 4)]);
        bf16x4 b1 = *reinterpret_cast<const bf16x4*>(
            &Vt[(32 + l31) * 64 + (((cb + 1) ^ d7) * 8 + hi * 4)]);
        bf16x8 vf1;
        #pragma unroll
        for (int e = 0; e < 4; ++e) { vf1[e] = a1[e]; vf1[4 + e] = b1[e]; }
        acc1 = __builtin_amdgcn_mfma_f32_32x32x16_bf16(pf, vf1, acc1, 0, 0, 0);
      }
    }
  }

  // epilogue: row q = (reg&3)+8*(reg>>2)+4*hi, col = l31 (+32 for dtile 1);
  // accS[reg] = full row sum (identical across cols) -> no shuffles
  #pragma unroll
  for (int reg = 0; reg < 16; ++reg) {
    int q_r = (reg & 3) + 8 * (reg >> 2) + 4 * hi;
    float rinv = 1.0f / accS[reg];
    size_t rowoff = ((size_t)b * 1024 + qrow0 + q_r) * 1024 + h * 64;
    aout[rowoff + l31]      = (bf16)(acc0[reg] * rinv);
    aout[rowoff + 32 + l31] = (bf16)(acc1[reg] * rinv);
  }
}

// ---------------- launch ----------------

extern "C" void kernel_launch(void* const* d_in, const int* in_sizes, int n_in,
                              void* d_out, int out_size, void* d_ws, size_t ws_size,
                              hipStream_t stream) {
  const float* x     = (const float*)d_in[0];   // [8,1024,1024]
  const float* w_in  = (const float*)d_in[1];   // [1024,3072]
  const float* w_out = (const float*)d_in[2];   // [1024,1024]
  const float* b_out = (const float*)d_in[3];   // [1024]
  float* out = (float*)d_out;                   // [8,1024,1024] fp32

  bf16* xb    = (bf16*)d_ws;                         // 8192*1024
  bf16* wint  = xb    + (size_t)8192 * 1024;         // 3072*1024  (w_in^T)
  bf16* woutt = wint  + (size_t)3072 * 1024;         // 1024*1024  (w_out^T)
  bf16* qkv   = woutt + (size_t)1024 * 1024;         // 8192*3072
  bf16* ao    = qkv   + (size_t)8192 * 3072;         // 8192*1024

  cvt_f32_to_bf16<<<8192, 256, 0, stream>>>(x, xb, 8192 * 1024);
  transpose_cvt<<<dim3(96, 32), dim3(32, 8), 0, stream>>>(w_in,  wint,  1024, 3072);
  transpose_cvt<<<dim3(32, 32), dim3(32, 8), 0, stream>>>(w_out, woutt, 1024, 1024);

  // qkv = x @ w_in   (bf16 out)
  gemm_abt<bf16, false><<<dim3(24, 64), 256, 0, stream>>>(xb, wint, nullptr, qkv, 8192, 3072, 1024);

  // fused attention -> ao (bf16, [token][h*64+d])
  attn_fused<<<1024, 256, 0, stream>>>(qkv, ao);

  // out = ao @ w_out + b_out   (fp32 out)
  gemm_abt<float, true><<<dim3(8, 64), 256, 0, stream>>>(ao, woutt, b_out, out, 8192, 1024, 1024);
}